// Round 17
// baseline (573.683 us; speedup 1.0000x reference)
//
#include <hip/hip_runtime.h>
#include <hip/hip_bf16.h>

// VQ-VAE forward. R17: break co-resident-block phase-lock — chunk-order
// rotation by block parity (commutative sum, exact) in dec2f + conv_mx3;
// dec2f LDS alias (LW on XL, 56.8->34 KB). conv_mx3 back to DB=0.

typedef unsigned short u16;
typedef unsigned int u32;
typedef unsigned long long u64;
typedef __attribute__((ext_vector_type(8))) short short8;
typedef __attribute__((ext_vector_type(4))) float f32x4;

__device__ __forceinline__ float bf2f(u16 u) {
    union { u32 i; float f; } x; x.i = ((u32)u) << 16; return x.f;
}
__device__ __forceinline__ u16 f2bf(float f) {
    __hip_bfloat16 h = __float2bfloat16(f);
    return *reinterpret_cast<u16*>(&h);
}

// ---------------------------------------------------------------------------
// Weight gathers (bf16, MFMA layouts).
// ---------------------------------------------------------------------------
__global__ void g_k3(const float* __restrict__ w, u16* __restrict__ wg,
                     int CIN, int COUT)   // OIHW k3: wg[(s*COUT+co)*CIN+ci]
{
    int idx = blockIdx.x * 256 + threadIdx.x;
    if (idx >= 9 * CIN * COUT) return;
    int ci = idx % CIN;
    int co = (idx / CIN) % COUT;
    int s  = idx / (CIN * COUT);
    wg[idx] = f2bf(w[(co * CIN + ci) * 9 + s]);
}

__global__ void g_enc2(const float* __restrict__ w, u16* __restrict__ wg)
{
    int idx = blockIdx.x * 256 + threadIdx.x;   // p(4) s(4) co(128) ci(128)
    int ci = idx & 127, co = (idx >> 7) & 127, s = (idx >> 14) & 3, p = idx >> 16;
    int a = p >> 1, b = p & 1, j = s >> 1, i = s & 1;
    int ky = (1 - a) + 2 * j, kx = (1 - b) + 2 * i;
    wg[idx] = f2bf(w[((co << 7 | ci) << 4) + ky * 4 + kx]);
}

__global__ void g_dec2(const float* __restrict__ w, u16* __restrict__ wg)
{
    int idx = blockIdx.x * 256 + threadIdx.x;   // p(4) s(4) co(128) ci(128)
    int ci = idx & 127, co = (idx >> 7) & 127, s = (idx >> 14) & 3, p = idx >> 16;
    int py = p >> 1, px = p & 1, j = s >> 1, i = s & 1;
    wg[idx] = f2bf(w[((ci << 7 | co) << 4) + (3 - (py + 2 * j)) * 4 + (3 - (px + 2 * i))]);
}

// dec3 parity-packed (R8, validated)
__global__ void g_dec3m(const float* __restrict__ w, u16* __restrict__ wg)
{
    int idx = blockIdx.x * 256 + threadIdx.x;   // 9*16*128 = 18432
    if (idx >= 18432) return;
    int ci  = idx & 127;
    int row = (idx >> 7) & 15;
    int t   = idx >> 11;
    int dy = t / 3 - 1, dx = t % 3 - 1;
    float v = 0.f;
    if (row < 12) {
        int p = row / 3, co = row % 3;
        int py = p >> 1, px = p & 1;
        int a = dy + 1 - py, b2 = dx + 1 - px;
        if (a >= 0 && a <= 1 && b2 >= 0 && b2 <= 1)
            v = w[((ci * 3 + co) * 4 + (3 - (py + 2 * a))) * 4 + (3 - (px + 2 * b2))];
    }
    wg[idx] = f2bf(v);
}

__global__ void g_enc1(const float* __restrict__ w, u16* __restrict__ wg)
{
    int idx = blockIdx.x * 256 + threadIdx.x;   // 128*64 = 8192
    if (idx >= 8192) return;
    int ci = idx & 3, kx = (idx >> 2) & 3, ky = (idx >> 4) & 3, co = idx >> 6;
    float v = 0.f;
    if (ci < 3) v = w[((co * 3 + ci) * 4 + ky) * 4 + kx];
    wg[idx] = f2bf(v);
}

__global__ void g_cbk(const float* __restrict__ cbk, u16* __restrict__ cb,
                      float* __restrict__ cn)
{
    int idx = blockIdx.x * 256 + threadIdx.x;   // 32768
    if (idx >= 32768) return;
    cb[idx] = f2bf(cbk[idx]);
    if (idx < 512) {
        float s = 0.f;
        const float* r = cbk + idx * 64;
        for (int i = 0; i < 64; i++) s += r[i] * r[i];
        cn[idx] = s;
    }
}

// x (fp32 NCHW) -> x_cl[n][258][258][4] bf16
__global__ __launch_bounds__(256) void xcl_k(
    const float* __restrict__ x, u16* __restrict__ xcl)
{
    const int y = blockIdx.x % 258, n = blockIdx.x / 258;
    const int gy = y - 1;
    for (int xx = threadIdx.x; xx < 258; xx += 256) {
        const int gx = xx - 1;
        u16 pk[4] = {0, 0, 0, 0};
        if (gy >= 0 && gy < 256 && gx >= 0 && gx < 256) {
            const size_t base = ((size_t)n * 3 * 256 + gy) * 256 + gx;
            pk[0] = f2bf(x[base]);
            pk[1] = f2bf(x[base + 65536]);
            pk[2] = f2bf(x[base + 131072]);
        }
        *(u64*)(xcl + ((size_t)(n * 258 + y) * 258 + xx) * 4) = *(const u64*)pk;
    }
}

// ---------------------------------------------------------------------------
// enc1 via MFMA (R7, validated).
// ---------------------------------------------------------------------------
__global__ __launch_bounds__(256) void enc1m_k(
    const u16* __restrict__ xcl, const u16* __restrict__ wg,
    const float* __restrict__ bias, u16* __restrict__ P)
{
    const int tid = threadIdx.x;
    const int l = tid & 63, w = tid >> 6;
    const int ln = l & 15, kg = l >> 4;
    const int px = w >> 1, half = w & 1;

    const int oy = blockIdx.x & 127;
    const int n  = blockIdx.x >> 7;
    const int p  = (oy & 1) * 2 + px;
    const int yy = oy >> 1;

    short8 af[8][2];
#pragma unroll
    for (int u = 0; u < 8; u++)
#pragma unroll
        for (int s = 0; s < 2; s++)
            af[u][s] = *(const short8*)(wg + ((u * 16 + ln) << 6) + s * 32 + 8 * kg);

    const u16* xn = xcl + (size_t)n * 258 * 258 * 4;
    const int r0 = 2 * oy;

#pragma unroll
    for (int t = 0; t < 2; t++) {
        const int xq = half * 32 + t * 16 + ln;
        const int ox = px + 2 * xq;

        short8 bf[2];
#pragma unroll
        for (int s = 0; s < 2; s++) {
            const int row = r0 + 2 * s + (kg >> 1);
            bf[s] = *(const short8*)(xn + ((size_t)row * 258 + 2 * ox) * 4
                                     + (kg & 1) * 8);
        }

        f32x4 acc[8];
#pragma unroll
        for (int u = 0; u < 8; u++) acc[u] = (f32x4){0.f, 0.f, 0.f, 0.f};
#pragma unroll
        for (int u = 0; u < 8; u++) {
            acc[u] = __builtin_amdgcn_mfma_f32_16x16x32_bf16(af[u][0], bf[0], acc[u], 0, 0, 0);
            acc[u] = __builtin_amdgcn_mfma_f32_16x16x32_bf16(af[u][1], bf[1], acc[u], 0, 0, 0);
        }

#pragma unroll
        for (int u = 0; u < 8; u++) {
            const int cobase = u * 16 + 4 * kg;
            u16 pk[4];
#pragma unroll
            for (int r = 0; r < 4; r++)
                pk[r] = f2bf(fmaxf(acc[u][r] + bias[cobase + r], 0.f));
            *(u64*)(P + ((((size_t)(n * 4 + p) * 64 + yy) * 64 + xq) << 7) + cobase)
                = *(const u64*)pk;
        }
    }
}

// ---------------------------------------------------------------------------
// conv_mx3 (single-buffer) + chunk-order rotation by block parity.
// ---------------------------------------------------------------------------
template<int J, int I, int NP, int NCW, int CI, int OUTM>
__global__ __launch_bounds__(512) void conv_mx3(
    const u16* __restrict__ x, const u16* __restrict__ wg,
    const float* __restrict__ bias, void* __restrict__ yv,
    int COUT)
{
    constexpr int G = 8 / NCW;
    constexpr int RS = 2 * G + 2;
    constexpr int TASKS = RS * 68 * 4;
    constexpr int SLOTS = (TASKS + 511) / 512;
    constexpr int CHP = CI / 32;
    constexpr int NCHUNK = NP * CHP;          // 16, 4, or 2 (power of 2)
    __shared__ u16 XL[RS * 68 * 40];

    const int tid = threadIdx.x;
    const int l = tid & 63, wv = tid >> 6;
    const int kg = l >> 4, ln = l & 15;
    const int cw = wv % NCW, g = wv / NCW;

    int b = blockIdx.x;
    constexpr int TILES = 64 / (2 * G);
    const int tile = b % TILES;  b /= TILES;
    const int n = b;
    const int OY0 = tile * (2 * G);
    const int ROT = (blockIdx.x & 1) * (NCHUNK / 2);

    bool valid[SLOTS], okm[SLOTS];
    int goff[SLOTS], loff[SLOTS];
#pragma unroll
    for (int s = 0; s < SLOTS; s++) {
        const int idx = s * 512 + tid;
        valid[s] = idx < TASKS;
        const int q = idx & 3, cc = (idx >> 2) % 68, r = (idx >> 2) / 68;
        const int gr = OY0 - 1 + r, gx = cc - 1;
        okm[s] = valid[s] && gr >= 0 && gr < 64 && gx >= 0 && gx < 64;
        goff[s] = okm[s] ? ((gr * 64 + gx) * CI + 8 * q) : 0;
        loff[s] = (r * 68 + cc) * 40 + 8 * q;
    }

    f32x4 acc[2][8];
#pragma unroll
    for (int u = 0; u < 2; u++)
#pragma unroll
        for (int t = 0; t < 8; t++) acc[u][t] = (f32x4){0.f, 0.f, 0.f, 0.f};

    const u16* xn = x + (size_t)n * NP * CI * 4096;
    const int co0 = cw * 32 + ln;
    const short8 z8 = (short8){0, 0, 0, 0, 0, 0, 0, 0};

    short8 pf[SLOTS];

#define LOADCHUNK(cidx)                                                      \
    {                                                                        \
        const u16* xp = xn + (size_t)((cidx) / CHP) * CI * 4096              \
                        + ((cidx) % CHP) * 32;                               \
        _Pragma("unroll")                                                    \
        for (int s = 0; s < SLOTS; s++)                                      \
            pf[s] = okm[s] ? *(const short8*)(xp + goff[s]) : z8;            \
    }

    LOADCHUNK(ROT);
#pragma unroll 1
    for (int q2 = 0; q2 < NCHUNK; q2++) {
        const int c = (q2 + ROT) & (NCHUNK - 1);
        __syncthreads();
#pragma unroll
        for (int s = 0; s < SLOTS; s++)
            if (valid[s]) *(short8*)(XL + loff[s]) = pf[s];
        __syncthreads();

        if (q2 + 1 < NCHUNK) LOADCHUNK((q2 + 1 + ROT) & (NCHUNK - 1));

        const int p = c / CHP;
        const int ci0 = (c % CHP) * 32;
        int dy0, dx0;
        const u16* wgp;
        if (NP == 4) {
            dy0 = -(p >> 1); dx0 = -(p & 1);
            wgp = wg + (size_t)p * J * I * COUT * CI;
        } else {
            dy0 = -1; dx0 = -1; wgp = wg;
        }

#pragma unroll
        for (int jv = 0; jv < J; jv++) {
            short8 wf0[I], wf1[I];
#pragma unroll
            for (int i = 0; i < I; i++) {
                const size_t wb = ((size_t)(jv * I + i) * COUT + co0)
                                  * CI + ci0 + 8 * kg;
                wf0[i] = *(const short8*)(wgp + wb);
                wf1[i] = *(const short8*)(wgp + wb + (size_t)16 * CI);
            }
#pragma unroll
            for (int i = 0; i < I; i++) {
#pragma unroll
                for (int t = 0; t < 8; t++) {
                    const int rf = (t >> 2) + 2 * g + dy0 + 1 + jv;
                    const int cf = (t & 3) * 16 + ln + dx0 + 1 + i;
                    const short8 bf = *(const short8*)(
                        XL + (rf * 68 + cf) * 40 + 8 * kg);
                    acc[0][t] = __builtin_amdgcn_mfma_f32_16x16x32_bf16(
                        wf0[i], bf, acc[0][t], 0, 0, 0);
                    acc[1][t] = __builtin_amdgcn_mfma_f32_16x16x32_bf16(
                        wf1[i], bf, acc[1][t], 0, 0, 0);
                }
            }
        }
    }
#undef LOADCHUNK

#pragma unroll
    for (int u = 0; u < 2; u++) {
        const int cob = cw * 32 + u * 16 + 4 * kg;
#pragma unroll
        for (int t = 0; t < 8; t++) {
            const int oy = OY0 + 2 * g + (t >> 2);
            const int ox = (t & 3) * 16 + ln;
            if constexpr (OUTM == 1) {
                float* out = (float*)yv;
#pragma unroll
                for (int rr = 0; rr < 4; rr++)
                    out[(((size_t)n * COUT + cob + rr) * 64 + oy) * 64 + ox]
                        = acc[u][t][rr] + bias[cob + rr];
            } else {
                u16 pk[4];
#pragma unroll
                for (int rr = 0; rr < 4; rr++)
                    pk[rr] = f2bf(fmaxf(acc[u][t][rr] + bias[cob + rr], 0.f));
                *(u64*)((u16*)yv + ((size_t)(n * 64 + oy) * 64 + ox) * COUT
                        + cob) = *(const u64*)pk;
            }
        }
    }
}

// ---------------------------------------------------------------------------
// dec2f (R17): R12 compute + chunk rotation by block parity + LW aliased on
// XL (LDS 34 KB). LDS-transpose epilogue (full-line stores).
// ---------------------------------------------------------------------------
__global__ __launch_bounds__(512) void dec2f_k(
    const u16* __restrict__ x, const u16* __restrict__ wg,
    const float* __restrict__ bias, u16* __restrict__ y)
{
    constexpr int RS = 4;
    constexpr int TASKS = RS * 68 * 4;       // 1088
    constexpr int SLOTS = 3;
    __shared__ u16 SH[8 * 16 * 136];         // 34,816 B; XL (21,760 B) aliases
    u16* XL = SH;
    u16* LW = SH;

    const int tid = threadIdx.x;
    const int l = tid & 63, wv = tid >> 6;
    const int kg = l >> 4, ln = l & 15;
    const int pc = wv & 3, ch = wv >> 2;
    const int py = pc >> 1, px = pc & 1;

    int b = blockIdx.x;
    const int tile = b & 31;  b >>= 5;
    const int n = b;
    const int OY0 = tile * 2;
    const int ROT = (blockIdx.x & 1) * 2;

    bool valid[SLOTS], okm[SLOTS];
    int goff[SLOTS], loff[SLOTS];
#pragma unroll
    for (int s = 0; s < SLOTS; s++) {
        const int idx = s * 512 + tid;
        valid[s] = idx < TASKS;
        const int q = idx & 3, cc = (idx >> 2) % 68, r = (idx >> 2) / 68;
        const int gr = OY0 - 1 + r, gx = cc - 1;
        okm[s] = valid[s] && gr >= 0 && gr < 64 && gx >= 0 && gx < 64;
        goff[s] = okm[s] ? ((gr * 64 + gx) * 128 + 8 * q) : 0;
        loff[s] = (r * 68 + cc) * 40 + 8 * q;
    }

    f32x4 acc[8][4];
#pragma unroll
    for (int u = 0; u < 8; u++)
#pragma unroll
        for (int t = 0; t < 4; t++) acc[u][t] = (f32x4){0.f, 0.f, 0.f, 0.f};

    const u16* xn = x + (size_t)n * 64 * 64 * 128;
    const short8 z8 = (short8){0, 0, 0, 0, 0, 0, 0, 0};
    const u16* wgp = wg + (size_t)pc * 4 * 128 * 128;

    short8 pf[SLOTS];
#pragma unroll
    for (int s = 0; s < SLOTS; s++)
        pf[s] = okm[s] ? *(const short8*)(xn + ROT * 32 + goff[s]) : z8;

#pragma unroll 1
    for (int q2 = 0; q2 < 4; q2++) {
        const int c = (q2 + ROT) & 3;
        __syncthreads();
#pragma unroll
        for (int s = 0; s < SLOTS; s++)
            if (valid[s]) *(short8*)(XL + loff[s]) = pf[s];
        __syncthreads();

        if (q2 < 3) {
            const u16* xp = xn + (((q2 + 1 + ROT) & 3) * 32);
#pragma unroll
            for (int s = 0; s < SLOTS; s++)
                pf[s] = okm[s] ? *(const short8*)(xp + goff[s]) : z8;
        }

        const int ci0 = c * 32;

        short8 B3[3][2][2];
#pragma unroll
        for (int rw = 0; rw < 3; rw++) {
            const int rf = py + rw;
#pragma unroll
            for (int cb = 0; cb < 2; cb++) {
                const int cf0 = ch * 32 + cb * 16 + ln + px;
#pragma unroll
                for (int sh = 0; sh < 2; sh++)
                    B3[rw][sh][cb] = *(const short8*)(
                        XL + (rf * 68 + cf0 + sh) * 40 + 8 * kg);
            }
        }

#pragma unroll
        for (int u = 0; u < 8; u++) {
            short8 wf[4];
#pragma unroll
            for (int s4 = 0; s4 < 4; s4++)
                wf[s4] = *(const short8*)(
                    wgp + ((size_t)s4 * 128 + u * 16 + ln) * 128 + ci0 + 8 * kg);
#pragma unroll
            for (int m = 0; m < 2; m++)
#pragma unroll
                for (int cb = 0; cb < 2; cb++)
#pragma unroll
                    for (int j = 0; j < 2; j++)
#pragma unroll
                        for (int i = 0; i < 2; i++)
                            acc[u][m * 2 + cb] =
                                __builtin_amdgcn_mfma_f32_16x16x32_bf16(
                                    wf[j * 2 + i], B3[m + j][i][cb],
                                    acc[u][m * 2 + cb], 0, 0, 0);
        }
    }

    // all waves done reading XL before LW alias reuse
    __syncthreads();

    // epilogue: LDS transpose per t-round, then contiguous 16B/lane stores.
    u16* lw = LW + wv * 16 * 136;
    const int q4 = l >> 4, ln15 = l & 15;
#pragma unroll
    for (int t = 0; t < 4; t++) {
        const int m = t >> 1, cb = t & 1;
#pragma unroll
        for (int u = 0; u < 8; u++) {
            const int cob = u * 16 + 4 * kg;
            u16 pk[4];
#pragma unroll
            for (int rr = 0; rr < 4; rr++)
                pk[rr] = f2bf(fmaxf(acc[u][t][rr] + bias[cob + rr], 0.f));
            *(u64*)(lw + ln * 136 + cob) = *(const u64*)pk;
        }
        asm volatile("s_waitcnt lgkmcnt(0)" ::: "memory");
        __builtin_amdgcn_sched_barrier(0);
        const int OY = 2 * (OY0 + m) + py;
#pragma unroll
        for (int rr2 = 0; rr2 < 4; rr2++) {
            const int pos = rr2 * 4 + q4;
            const short8 v = *(const short8*)(lw + pos * 136 + ln15 * 8);
            const int ox = ch * 32 + cb * 16 + pos;
            const int OX = 2 * ox + px;
            *(short8*)(y + ((size_t)(n * 128 + OY) * 128 + OX) * 128 + ln15 * 8) = v;
        }
        asm volatile("s_waitcnt lgkmcnt(0)" ::: "memory");
        __builtin_amdgcn_sched_barrier(0);
    }
}

// ---------------------------------------------------------------------------
// dec3m (R8, validated): deconv3 via parity-packed MFMA.
// ---------------------------------------------------------------------------
__global__ __launch_bounds__(256) void dec3m_k(
    const u16* __restrict__ A2, const u16* __restrict__ wg,
    const float* __restrict__ bias, float* __restrict__ out)
{
    const int tid = threadIdx.x;
    const int l = tid & 63, wvi = tid >> 6;
    const int ln = l & 15, kg = l >> 4;

    int b = blockIdx.x;
    const int mxT = b & 7;  b >>= 3;
    const int myT = b & 3;  b >>= 2;
    const int n = b;
    const int X0 = mxT * 16;
    const int MY0 = myT * 32 + wvi * 8;
    const int xx = X0 + ln;

    const short8 z8 = (short8){0, 0, 0, 0, 0, 0, 0, 0};

    f32x4 acc[8];
#pragma unroll
    for (int m = 0; m < 8; m++) acc[m] = (f32x4){0.f, 0.f, 0.f, 0.f};

    int xoff[3]; bool xok[3];
#pragma unroll
    for (int sh = 0; sh < 3; sh++) {
        const int xv = xx + sh - 1;
        xok[sh] = (xv >= 0) & (xv < 128);
        xoff[sh] = (xok[sh] ? xv : 0) << 7;
    }

    for (int ks = 0; ks < 4; ks++) {
        const int cio = ks * 32 + 8 * kg;

        short8 at[9];
#pragma unroll
        for (int t = 0; t < 9; t++)
            at[t] = *(const short8*)(wg + (((size_t)t * 16 + ln) << 7) + cio);

        short8 B[10][3];
#pragma unroll
        for (int r = 0; r < 10; r++) {
            const int yy = MY0 - 1 + r;
            const bool yok = (yy >= 0) & (yy < 128);
            const size_t rowb = ((size_t)(n * 128 + (yok ? yy : 0)) << 7 << 7);
#pragma unroll
            for (int sh = 0; sh < 3; sh++) {
                short8 v = *(const short8*)(A2 + rowb + xoff[sh] + cio);
                B[r][sh] = (yok & xok[sh]) ? v : z8;
            }
            if (r >= 2) {
                const int m = r - 2;
#pragma unroll
                for (int rr = 0; rr < 3; rr++)
#pragma unroll
                    for (int sh = 0; sh < 3; sh++)
                        acc[m] = __builtin_amdgcn_mfma_f32_16x16x32_bf16(
                            at[rr * 3 + sh], B[m + rr][sh], acc[m], 0, 0, 0);
            }
        }
    }

    if (kg < 3) {
#pragma unroll
        for (int m = 0; m < 8; m++) {
            const int my = MY0 + m;
#pragma unroll
            for (int rr = 0; rr < 4; rr++) {
                const int row = 4 * kg + rr;
                const int p = row / 3, co = row % 3;
                const int oy = 2 * my + (p >> 1);
                const int ox = 2 * xx + (p & 1);
                out[(((size_t)(n * 3 + co)) << 16) + oy * 256 + ox]
                    = acc[m][rr] + bias[co];
            }
        }
    }
}

// ---------------------------------------------------------------------------
// vqm2 (R10, validated): VQ via MFMA GEMM; writes zq fp32 NCHW + bf16 CL copy.
// ---------------------------------------------------------------------------
__global__ __launch_bounds__(256) void vqm2_k(
    const float* __restrict__ ze, const u16* __restrict__ cb,
    const float* __restrict__ cn, const float* __restrict__ cbk,
    float* __restrict__ zq, u16* __restrict__ zqcl)
{
    __shared__ float CN[512];
    __shared__ int IDX[64];
    __shared__ u16 CLDS[64][66];
    const int tid = threadIdx.x;
    const int l = tid & 63, wvi = tid >> 6;
    const int ln = l & 15, kg = l >> 4;

    const int n = blockIdx.x >> 6, y = blockIdx.x & 63;

    for (int i = tid; i < 512; i += 256) CN[i] = cn[i];
    __syncthreads();

    short8 az[2];
#pragma unroll
    for (int ks = 0; ks < 2; ks++) {
        const float* zp = ze + ((size_t)(n * 64 + wvi * 16 + ln) * 64 + y) * 64
                          + ks * 32 + 8 * kg;
        short8 t;
#pragma unroll
        for (int j = 0; j < 8; j++) t[j] = (short)f2bf(zp[j]);
        az[ks] = t;
    }

    float bval[4] = {3.4e38f, 3.4e38f, 3.4e38f, 3.4e38f};
    int bidx[4] = {0, 0, 0, 0};
    for (int nt = 0; nt < 32; nt++) {
        const int code = nt * 16 + ln;
        const short8 b0 = *(const short8*)(cb + (size_t)code * 64 + 8 * kg);
        const short8 b1 = *(const short8*)(cb + (size_t)code * 64 + 32 + 8 * kg);
        f32x4 d = (f32x4){0.f, 0.f, 0.f, 0.f};
        d = __builtin_amdgcn_mfma_f32_16x16x32_bf16(az[0], b0, d, 0, 0, 0);
        d = __builtin_amdgcn_mfma_f32_16x16x32_bf16(az[1], b1, d, 0, 0, 0);
        const float cnv = CN[code];
#pragma unroll
        for (int r = 0; r < 4; r++) {
            const float dist = cnv - 2.f * d[r];
            if (dist < bval[r]) { bval[r] = dist; bidx[r] = code; }
        }
    }
#pragma unroll
    for (int off = 1; off < 16; off <<= 1) {
#pragma unroll
        for (int r = 0; r < 4; r++) {
            const float ov = __shfl_xor(bval[r], off);
            const int oi = __shfl_xor(bidx[r], off);
            if (ov < bval[r] || (ov == bval[r] && oi < bidx[r])) {
                bval[r] = ov; bidx[r] = oi;
            }
        }
    }
    if (ln == 0) {
#pragma unroll
        for (int r = 0; r < 4; r++) IDX[wvi * 16 + 4 * kg + r] = bidx[r];
    }
    __syncthreads();

    {
        const int ci = tid >> 2, ch4 = tid & 3;
        const int bi = IDX[ci];
        const float4* sp = (const float4*)(cbk + (size_t)bi * 64 + ch4 * 16);
        float4* dp = (float4*)(zq + ((size_t)(n * 64 + ci) * 64 + y) * 64 + ch4 * 16);
#pragma unroll
        for (int q = 0; q < 4; q++) dp[q] = sp[q];
    }

    for (int idx = tid; idx < 4096; idx += 256) {
        const int ci = idx >> 6, xx = idx & 63;
        CLDS[ci][xx] = cb[(size_t)IDX[ci] * 64 + xx];
    }
    __syncthreads();
    for (int idx = tid; idx < 4096; idx += 256) {
        const int xx = idx >> 6, ci = idx & 63;
        zqcl[(((size_t)(n * 64 + y) * 64 + xx) << 6) + ci] = CLDS[ci][xx];
    }
}

// ---------------------------------------------------------------------------
extern "C" void kernel_launch(void* const* d_in, const int* in_sizes, int n_in,
                              void* d_out, int out_size, void* d_ws, size_t ws_size,
                              hipStream_t stream)
{
    (void)in_sizes; (void)n_in; (void)out_size; (void)ws_size;

    const float* x   = (const float*)d_in[0];
    const float* ew1 = (const float*)d_in[1];
    const float* eb1 = (const float*)d_in[2];
    const float* ew2 = (const float*)d_in[3];
    const float* eb2 = (const float*)d_in[4];
    const float* ew3 = (const float*)d_in[5];
    const float* eb3 = (const float*)d_in[6];
    const float* cbk = (const float*)d_in[7];
    const float* dw1 = (const float*)d_in[8];
    const float* db1 = (const float*)d_in[9];
    const float* dw2 = (const float*)d_in[10];
    const float* db2 = (const float*)d_in[11];
    const float* dw3 = (const float*)d_in[12];
    const float* db3 = (const float*)d_in[13];

    u16* P    = (u16*)d_ws;
    u16* ZQCL = P;
    u16* A2   = P;
    u16* B = (u16*)((char*)d_ws + 134217728);
    u16* XCL = B;
    u16* Wg2 = (u16*)((char*)d_ws + 167772160);       // 262144
    u16* Wg3 = Wg2 + 262144;                          // 73728
    u16* Wg4 = Wg3 + 73728;                           // 73728
    u16* Wg5 = Wg4 + 73728;                           // 262144
    u16* Wg6 = Wg5 + 262144;                          // 18432 (dec3m)
    u16* CB  = Wg6 + 32768;                           // 32768
    u16* Wg1 = CB + 32768;                            // 8192
    float* CNg = (float*)(Wg1 + 8192);                // 512

    float* xr = (float*)d_out;
    float* ze = xr + (size_t)32 * 3 * 256 * 256;
    float* zq = ze + (size_t)32 * 64 * 64 * 64;

    g_enc1<<<32, 256, 0, stream>>>(ew1, Wg1);
    g_enc2<<<1024, 256, 0, stream>>>(ew2, Wg2);
    g_k3<<<288, 256, 0, stream>>>(ew3, Wg3, 128, 64);
    g_k3<<<288, 256, 0, stream>>>(dw1, Wg4, 64, 128);
    g_dec2<<<1024, 256, 0, stream>>>(dw2, Wg5);
    g_dec3m<<<72, 256, 0, stream>>>(dw3, Wg6);
    g_cbk<<<128, 256, 0, stream>>>(cbk, CB, CNg);

    xcl_k<<<32 * 258, 256, 0, stream>>>(x, XCL);
    enc1m_k<<<32 * 128, 256, 0, stream>>>(XCL, Wg1, eb1, P);
    // enc2: 4 planes k2 -> B (CL, relu), chunk-rotated
    conv_mx3<2, 2, 4, 4, 128, 0><<<32 * 16, 512, 0, stream>>>(P, Wg2, eb2, B, 128);
    // enc3: k3 -> ze (fp32), chunk-rotated
    conv_mx3<3, 3, 1, 2, 128, 1><<<32 * 8, 512, 0, stream>>>(B, Wg3, eb3, ze, 64);
    // VQ (writes zq fp32 + ZQCL bf16 CL)
    vqm2_k<<<2048, 256, 0, stream>>>(ze, CB, CNg, cbk, zq, ZQCL);
    // dec1: k3 -> B (CL, relu), chunk-rotated
    conv_mx3<3, 3, 1, 4, 64, 0><<<32 * 16, 512, 0, stream>>>(ZQCL, Wg4, db1, B, 128);
    // deconv2: chunk-rotated, LDS-aliased -> A2 (CL, relu)
    dec2f_k<<<1024, 512, 0, stream>>>(B, Wg5, db2, A2);
    // deconv3 -> x_recon
    dec3m_k<<<1024, 256, 0, stream>>>(A2, Wg6, db3, xr);
}

// Round 18
// 563.646 us; speedup vs baseline: 1.0178x; 1.0178x over previous
//
#include <hip/hip_runtime.h>
#include <hip/hip_bf16.h>

// VQ-VAE forward. R18 = R12 exact (session-best 563.5 us): conv_mx3 (R9),
// dec2f with shared B-window + LDS-transpose epilogue (separate LW),
// enc1m/dec3m/vqm2/xcl validated kernels. Locked-in configuration.

typedef unsigned short u16;
typedef unsigned int u32;
typedef unsigned long long u64;
typedef __attribute__((ext_vector_type(8))) short short8;
typedef __attribute__((ext_vector_type(4))) float f32x4;

__device__ __forceinline__ float bf2f(u16 u) {
    union { u32 i; float f; } x; x.i = ((u32)u) << 16; return x.f;
}
__device__ __forceinline__ u16 f2bf(float f) {
    __hip_bfloat16 h = __float2bfloat16(f);
    return *reinterpret_cast<u16*>(&h);
}

// ---------------------------------------------------------------------------
// Weight gathers (bf16, MFMA layouts).
// ---------------------------------------------------------------------------
__global__ void g_k3(const float* __restrict__ w, u16* __restrict__ wg,
                     int CIN, int COUT)   // OIHW k3: wg[(s*COUT+co)*CIN+ci]
{
    int idx = blockIdx.x * 256 + threadIdx.x;
    if (idx >= 9 * CIN * COUT) return;
    int ci = idx % CIN;
    int co = (idx / CIN) % COUT;
    int s  = idx / (CIN * COUT);
    wg[idx] = f2bf(w[(co * CIN + ci) * 9 + s]);
}

__global__ void g_enc2(const float* __restrict__ w, u16* __restrict__ wg)
{
    int idx = blockIdx.x * 256 + threadIdx.x;   // p(4) s(4) co(128) ci(128)
    int ci = idx & 127, co = (idx >> 7) & 127, s = (idx >> 14) & 3, p = idx >> 16;
    int a = p >> 1, b = p & 1, j = s >> 1, i = s & 1;
    int ky = (1 - a) + 2 * j, kx = (1 - b) + 2 * i;
    wg[idx] = f2bf(w[((co << 7 | ci) << 4) + ky * 4 + kx]);
}

__global__ void g_dec2(const float* __restrict__ w, u16* __restrict__ wg)
{
    int idx = blockIdx.x * 256 + threadIdx.x;   // p(4) s(4) co(128) ci(128)
    int ci = idx & 127, co = (idx >> 7) & 127, s = (idx >> 14) & 3, p = idx >> 16;
    int py = p >> 1, px = p & 1, j = s >> 1, i = s & 1;
    wg[idx] = f2bf(w[((ci << 7 | co) << 4) + (3 - (py + 2 * j)) * 4 + (3 - (px + 2 * i))]);
}

// dec3 parity-packed (R8, validated)
__global__ void g_dec3m(const float* __restrict__ w, u16* __restrict__ wg)
{
    int idx = blockIdx.x * 256 + threadIdx.x;   // 9*16*128 = 18432
    if (idx >= 18432) return;
    int ci  = idx & 127;
    int row = (idx >> 7) & 15;
    int t   = idx >> 11;
    int dy = t / 3 - 1, dx = t % 3 - 1;
    float v = 0.f;
    if (row < 12) {
        int p = row / 3, co = row % 3;
        int py = p >> 1, px = p & 1;
        int a = dy + 1 - py, b2 = dx + 1 - px;
        if (a >= 0 && a <= 1 && b2 >= 0 && b2 <= 1)
            v = w[((ci * 3 + co) * 4 + (3 - (py + 2 * a))) * 4 + (3 - (px + 2 * b2))];
    }
    wg[idx] = f2bf(v);
}

__global__ void g_enc1(const float* __restrict__ w, u16* __restrict__ wg)
{
    int idx = blockIdx.x * 256 + threadIdx.x;   // 128*64 = 8192
    if (idx >= 8192) return;
    int ci = idx & 3, kx = (idx >> 2) & 3, ky = (idx >> 4) & 3, co = idx >> 6;
    float v = 0.f;
    if (ci < 3) v = w[((co * 3 + ci) * 4 + ky) * 4 + kx];
    wg[idx] = f2bf(v);
}

__global__ void g_cbk(const float* __restrict__ cbk, u16* __restrict__ cb,
                      float* __restrict__ cn)
{
    int idx = blockIdx.x * 256 + threadIdx.x;   // 32768
    if (idx >= 32768) return;
    cb[idx] = f2bf(cbk[idx]);
    if (idx < 512) {
        float s = 0.f;
        const float* r = cbk + idx * 64;
        for (int i = 0; i < 64; i++) s += r[i] * r[i];
        cn[idx] = s;
    }
}

// x (fp32 NCHW) -> x_cl[n][258][258][4] bf16
__global__ __launch_bounds__(256) void xcl_k(
    const float* __restrict__ x, u16* __restrict__ xcl)
{
    const int y = blockIdx.x % 258, n = blockIdx.x / 258;
    const int gy = y - 1;
    for (int xx = threadIdx.x; xx < 258; xx += 256) {
        const int gx = xx - 1;
        u16 pk[4] = {0, 0, 0, 0};
        if (gy >= 0 && gy < 256 && gx >= 0 && gx < 256) {
            const size_t base = ((size_t)n * 3 * 256 + gy) * 256 + gx;
            pk[0] = f2bf(x[base]);
            pk[1] = f2bf(x[base + 65536]);
            pk[2] = f2bf(x[base + 131072]);
        }
        *(u64*)(xcl + ((size_t)(n * 258 + y) * 258 + xx) * 4) = *(const u64*)pk;
    }
}

// ---------------------------------------------------------------------------
// enc1 via MFMA (R7, validated).
// ---------------------------------------------------------------------------
__global__ __launch_bounds__(256) void enc1m_k(
    const u16* __restrict__ xcl, const u16* __restrict__ wg,
    const float* __restrict__ bias, u16* __restrict__ P)
{
    const int tid = threadIdx.x;
    const int l = tid & 63, w = tid >> 6;
    const int ln = l & 15, kg = l >> 4;
    const int px = w >> 1, half = w & 1;

    const int oy = blockIdx.x & 127;
    const int n  = blockIdx.x >> 7;
    const int p  = (oy & 1) * 2 + px;
    const int yy = oy >> 1;

    short8 af[8][2];
#pragma unroll
    for (int u = 0; u < 8; u++)
#pragma unroll
        for (int s = 0; s < 2; s++)
            af[u][s] = *(const short8*)(wg + ((u * 16 + ln) << 6) + s * 32 + 8 * kg);

    const u16* xn = xcl + (size_t)n * 258 * 258 * 4;
    const int r0 = 2 * oy;

#pragma unroll
    for (int t = 0; t < 2; t++) {
        const int xq = half * 32 + t * 16 + ln;
        const int ox = px + 2 * xq;

        short8 bf[2];
#pragma unroll
        for (int s = 0; s < 2; s++) {
            const int row = r0 + 2 * s + (kg >> 1);
            bf[s] = *(const short8*)(xn + ((size_t)row * 258 + 2 * ox) * 4
                                     + (kg & 1) * 8);
        }

        f32x4 acc[8];
#pragma unroll
        for (int u = 0; u < 8; u++) acc[u] = (f32x4){0.f, 0.f, 0.f, 0.f};
#pragma unroll
        for (int u = 0; u < 8; u++) {
            acc[u] = __builtin_amdgcn_mfma_f32_16x16x32_bf16(af[u][0], bf[0], acc[u], 0, 0, 0);
            acc[u] = __builtin_amdgcn_mfma_f32_16x16x32_bf16(af[u][1], bf[1], acc[u], 0, 0, 0);
        }

#pragma unroll
        for (int u = 0; u < 8; u++) {
            const int cobase = u * 16 + 4 * kg;
            u16 pk[4];
#pragma unroll
            for (int r = 0; r < 4; r++)
                pk[r] = f2bf(fmaxf(acc[u][r] + bias[cobase + r], 0.f));
            *(u64*)(P + ((((size_t)(n * 4 + p) * 64 + yy) * 64 + xq) << 7) + cobase)
                = *(const u64*)pk;
        }
    }
}

// ---------------------------------------------------------------------------
// conv_mx3 (R9, validated): used for enc2/enc3/dec1.
// ---------------------------------------------------------------------------
template<int J, int I, int NP, int NCW, int CI, int OUTM>
__global__ __launch_bounds__(512) void conv_mx3(
    const u16* __restrict__ x, const u16* __restrict__ wg,
    const float* __restrict__ bias, void* __restrict__ yv,
    int COUT)
{
    constexpr int G = 8 / NCW;
    constexpr int RS = 2 * G + 2;
    constexpr int TASKS = RS * 68 * 4;
    constexpr int SLOTS = (TASKS + 511) / 512;
    constexpr int CHP = CI / 32;
    constexpr int NCHUNK = NP * CHP;
    __shared__ u16 XL[RS * 68 * 40];

    const int tid = threadIdx.x;
    const int l = tid & 63, wv = tid >> 6;
    const int kg = l >> 4, ln = l & 15;
    const int cw = wv % NCW, g = wv / NCW;

    int b = blockIdx.x;
    constexpr int TILES = 64 / (2 * G);
    const int tile = b % TILES;  b /= TILES;
    const int n = b;
    const int OY0 = tile * (2 * G);

    bool valid[SLOTS], okm[SLOTS];
    int goff[SLOTS], loff[SLOTS];
#pragma unroll
    for (int s = 0; s < SLOTS; s++) {
        const int idx = s * 512 + tid;
        valid[s] = idx < TASKS;
        const int q = idx & 3, cc = (idx >> 2) % 68, r = (idx >> 2) / 68;
        const int gr = OY0 - 1 + r, gx = cc - 1;
        okm[s] = valid[s] && gr >= 0 && gr < 64 && gx >= 0 && gx < 64;
        goff[s] = okm[s] ? ((gr * 64 + gx) * CI + 8 * q) : 0;
        loff[s] = (r * 68 + cc) * 40 + 8 * q;
    }

    f32x4 acc[2][8];
#pragma unroll
    for (int u = 0; u < 2; u++)
#pragma unroll
        for (int t = 0; t < 8; t++) acc[u][t] = (f32x4){0.f, 0.f, 0.f, 0.f};

    const u16* xn = x + (size_t)n * NP * CI * 4096;
    const int co0 = cw * 32 + ln;
    const short8 z8 = (short8){0, 0, 0, 0, 0, 0, 0, 0};

    short8 pf[SLOTS];
    {
        const u16* xp = xn;
#pragma unroll
        for (int s = 0; s < SLOTS; s++)
            pf[s] = okm[s] ? *(const short8*)(xp + goff[s]) : z8;
    }

    for (int c = 0; c < NCHUNK; c++) {
        __syncthreads();
#pragma unroll
        for (int s = 0; s < SLOTS; s++)
            if (valid[s]) *(short8*)(XL + loff[s]) = pf[s];
        __syncthreads();

        if (c + 1 < NCHUNK) {
            const int cn_ = c + 1;
            const u16* xp = xn + (size_t)(cn_ / CHP) * CI * 4096
                            + (cn_ % CHP) * 32;
#pragma unroll
            for (int s = 0; s < SLOTS; s++)
                pf[s] = okm[s] ? *(const short8*)(xp + goff[s]) : z8;
        }

        const int p = c / CHP;
        const int ci0 = (c % CHP) * 32;
        int dy0, dx0;
        const u16* wgp;
        if (NP == 4) {
            dy0 = -(p >> 1); dx0 = -(p & 1);
            wgp = wg + (size_t)p * J * I * COUT * CI;
        } else {
            dy0 = -1; dx0 = -1; wgp = wg;
        }

#define TAP_ROW(jv)                                                          \
        {                                                                    \
            short8 wf0[I], wf1[I];                                           \
            _Pragma("unroll")                                                \
            for (int i = 0; i < I; i++) {                                    \
                const size_t wb = ((size_t)((jv) * I + i) * COUT + co0)      \
                                  * CI + ci0 + 8 * kg;                       \
                wf0[i] = *(const short8*)(wgp + wb);                         \
                wf1[i] = *(const short8*)(wgp + wb + (size_t)16 * CI);       \
            }                                                                \
            _Pragma("unroll")                                                \
            for (int i = 0; i < I; i++) {                                    \
                _Pragma("unroll")                                            \
                for (int t = 0; t < 8; t++) {                                \
                    const int rf = (t >> 2) + 2 * g + dy0 + 1 + (jv);        \
                    const int cf = (t & 3) * 16 + ln + dx0 + 1 + i;          \
                    const short8 bf = *(const short8*)(                      \
                        XL + (rf * 68 + cf) * 40 + 8 * kg);                  \
                    acc[0][t] = __builtin_amdgcn_mfma_f32_16x16x32_bf16(     \
                        wf0[i], bf, acc[0][t], 0, 0, 0);                     \
                    acc[1][t] = __builtin_amdgcn_mfma_f32_16x16x32_bf16(     \
                        wf1[i], bf, acc[1][t], 0, 0, 0);                     \
                }                                                            \
            }                                                                \
        }

        if constexpr (J == 2) {
            TAP_ROW(0); TAP_ROW(1);
        } else {
            TAP_ROW(0); TAP_ROW(1); TAP_ROW(2);
        }
#undef TAP_ROW
    }

#pragma unroll
    for (int u = 0; u < 2; u++) {
        const int cob = cw * 32 + u * 16 + 4 * kg;
#pragma unroll
        for (int t = 0; t < 8; t++) {
            const int oy = OY0 + 2 * g + (t >> 2);
            const int ox = (t & 3) * 16 + ln;
            if constexpr (OUTM == 1) {
                float* out = (float*)yv;
#pragma unroll
                for (int rr = 0; rr < 4; rr++)
                    out[(((size_t)n * COUT + cob + rr) * 64 + oy) * 64 + ox]
                        = acc[u][t][rr] + bias[cob + rr];
            } else {
                u16 pk[4];
#pragma unroll
                for (int rr = 0; rr < 4; rr++)
                    pk[rr] = f2bf(fmaxf(acc[u][t][rr] + bias[cob + rr], 0.f));
                *(u64*)((u16*)yv + ((size_t)(n * 64 + oy) * 64 + ox) * COUT
                        + cob) = *(const u64*)pk;
            }
        }
    }
}

// ---------------------------------------------------------------------------
// dec2f (R12 exact, session-best): parity-per-wave, shared B-window,
// per-chunk staging, LDS-transpose epilogue (full-line stores).
// ---------------------------------------------------------------------------
__global__ __launch_bounds__(512) void dec2f_k(
    const u16* __restrict__ x, const u16* __restrict__ wg,
    const float* __restrict__ bias, u16* __restrict__ y)
{
    constexpr int RS = 4;
    constexpr int TASKS = RS * 68 * 4;       // 1088
    constexpr int SLOTS = 3;
    __shared__ u16 XL[RS * 68 * 40];
    __shared__ u16 LW[8 * 16 * 136];

    const int tid = threadIdx.x;
    const int l = tid & 63, wv = tid >> 6;
    const int kg = l >> 4, ln = l & 15;
    const int pc = wv & 3, ch = wv >> 2;
    const int py = pc >> 1, px = pc & 1;

    int b = blockIdx.x;
    const int tile = b & 31;  b >>= 5;
    const int n = b;
    const int OY0 = tile * 2;

    bool valid[SLOTS], okm[SLOTS];
    int goff[SLOTS], loff[SLOTS];
#pragma unroll
    for (int s = 0; s < SLOTS; s++) {
        const int idx = s * 512 + tid;
        valid[s] = idx < TASKS;
        const int q = idx & 3, cc = (idx >> 2) % 68, r = (idx >> 2) / 68;
        const int gr = OY0 - 1 + r, gx = cc - 1;
        okm[s] = valid[s] && gr >= 0 && gr < 64 && gx >= 0 && gx < 64;
        goff[s] = okm[s] ? ((gr * 64 + gx) * 128 + 8 * q) : 0;
        loff[s] = (r * 68 + cc) * 40 + 8 * q;
    }

    f32x4 acc[8][4];
#pragma unroll
    for (int u = 0; u < 8; u++)
#pragma unroll
        for (int t = 0; t < 4; t++) acc[u][t] = (f32x4){0.f, 0.f, 0.f, 0.f};

    const u16* xn = x + (size_t)n * 64 * 64 * 128;
    const short8 z8 = (short8){0, 0, 0, 0, 0, 0, 0, 0};
    const u16* wgp = wg + (size_t)pc * 4 * 128 * 128;

    short8 pf[SLOTS];
#pragma unroll
    for (int s = 0; s < SLOTS; s++)
        pf[s] = okm[s] ? *(const short8*)(xn + goff[s]) : z8;

    for (int c = 0; c < 4; c++) {
        __syncthreads();
#pragma unroll
        for (int s = 0; s < SLOTS; s++)
            if (valid[s]) *(short8*)(XL + loff[s]) = pf[s];
        __syncthreads();

        if (c < 3) {
            const u16* xp = xn + (c + 1) * 32;
#pragma unroll
            for (int s = 0; s < SLOTS; s++)
                pf[s] = okm[s] ? *(const short8*)(xp + goff[s]) : z8;
        }

        const int ci0 = c * 32;

        short8 B3[3][2][2];
#pragma unroll
        for (int rw = 0; rw < 3; rw++) {
            const int rf = py + rw;
#pragma unroll
            for (int cb = 0; cb < 2; cb++) {
                const int cf0 = ch * 32 + cb * 16 + ln + px;
#pragma unroll
                for (int sh = 0; sh < 2; sh++)
                    B3[rw][sh][cb] = *(const short8*)(
                        XL + (rf * 68 + cf0 + sh) * 40 + 8 * kg);
            }
        }

#pragma unroll
        for (int u = 0; u < 8; u++) {
            short8 wf[4];
#pragma unroll
            for (int s4 = 0; s4 < 4; s4++)
                wf[s4] = *(const short8*)(
                    wgp + ((size_t)s4 * 128 + u * 16 + ln) * 128 + ci0 + 8 * kg);
#pragma unroll
            for (int m = 0; m < 2; m++)
#pragma unroll
                for (int cb = 0; cb < 2; cb++)
#pragma unroll
                    for (int j = 0; j < 2; j++)
#pragma unroll
                        for (int i = 0; i < 2; i++)
                            acc[u][m * 2 + cb] =
                                __builtin_amdgcn_mfma_f32_16x16x32_bf16(
                                    wf[j * 2 + i], B3[m + j][i][cb],
                                    acc[u][m * 2 + cb], 0, 0, 0);
        }
    }

    // epilogue: LDS transpose per t-round, then contiguous 16B/lane stores.
    u16* lw = LW + wv * 16 * 136;
    const int q4 = l >> 4, ln15 = l & 15;
#pragma unroll
    for (int t = 0; t < 4; t++) {
        const int m = t >> 1, cb = t & 1;
#pragma unroll
        for (int u = 0; u < 8; u++) {
            const int cob = u * 16 + 4 * kg;
            u16 pk[4];
#pragma unroll
            for (int rr = 0; rr < 4; rr++)
                pk[rr] = f2bf(fmaxf(acc[u][t][rr] + bias[cob + rr], 0.f));
            *(u64*)(lw + ln * 136 + cob) = *(const u64*)pk;
        }
        asm volatile("s_waitcnt lgkmcnt(0)" ::: "memory");
        __builtin_amdgcn_sched_barrier(0);
        const int OY = 2 * (OY0 + m) + py;
#pragma unroll
        for (int rr2 = 0; rr2 < 4; rr2++) {
            const int pos = rr2 * 4 + q4;
            const short8 v = *(const short8*)(lw + pos * 136 + ln15 * 8);
            const int ox = ch * 32 + cb * 16 + pos;
            const int OX = 2 * ox + px;
            *(short8*)(y + ((size_t)(n * 128 + OY) * 128 + OX) * 128 + ln15 * 8) = v;
        }
        asm volatile("s_waitcnt lgkmcnt(0)" ::: "memory");
        __builtin_amdgcn_sched_barrier(0);
    }
}

// ---------------------------------------------------------------------------
// dec3m (R8, validated): deconv3 via parity-packed MFMA.
// ---------------------------------------------------------------------------
__global__ __launch_bounds__(256) void dec3m_k(
    const u16* __restrict__ A2, const u16* __restrict__ wg,
    const float* __restrict__ bias, float* __restrict__ out)
{
    const int tid = threadIdx.x;
    const int l = tid & 63, wvi = tid >> 6;
    const int ln = l & 15, kg = l >> 4;

    int b = blockIdx.x;
    const int mxT = b & 7;  b >>= 3;
    const int myT = b & 3;  b >>= 2;
    const int n = b;
    const int X0 = mxT * 16;
    const int MY0 = myT * 32 + wvi * 8;
    const int xx = X0 + ln;

    const short8 z8 = (short8){0, 0, 0, 0, 0, 0, 0, 0};

    f32x4 acc[8];
#pragma unroll
    for (int m = 0; m < 8; m++) acc[m] = (f32x4){0.f, 0.f, 0.f, 0.f};

    int xoff[3]; bool xok[3];
#pragma unroll
    for (int sh = 0; sh < 3; sh++) {
        const int xv = xx + sh - 1;
        xok[sh] = (xv >= 0) & (xv < 128);
        xoff[sh] = (xok[sh] ? xv : 0) << 7;
    }

    for (int ks = 0; ks < 4; ks++) {
        const int cio = ks * 32 + 8 * kg;

        short8 at[9];
#pragma unroll
        for (int t = 0; t < 9; t++)
            at[t] = *(const short8*)(wg + (((size_t)t * 16 + ln) << 7) + cio);

        short8 B[10][3];
#pragma unroll
        for (int r = 0; r < 10; r++) {
            const int yy = MY0 - 1 + r;
            const bool yok = (yy >= 0) & (yy < 128);
            const size_t rowb = ((size_t)(n * 128 + (yok ? yy : 0)) << 7 << 7);
#pragma unroll
            for (int sh = 0; sh < 3; sh++) {
                short8 v = *(const short8*)(A2 + rowb + xoff[sh] + cio);
                B[r][sh] = (yok & xok[sh]) ? v : z8;
            }
            if (r >= 2) {
                const int m = r - 2;
#pragma unroll
                for (int rr = 0; rr < 3; rr++)
#pragma unroll
                    for (int sh = 0; sh < 3; sh++)
                        acc[m] = __builtin_amdgcn_mfma_f32_16x16x32_bf16(
                            at[rr * 3 + sh], B[m + rr][sh], acc[m], 0, 0, 0);
            }
        }
    }

    if (kg < 3) {
#pragma unroll
        for (int m = 0; m < 8; m++) {
            const int my = MY0 + m;
#pragma unroll
            for (int rr = 0; rr < 4; rr++) {
                const int row = 4 * kg + rr;
                const int p = row / 3, co = row % 3;
                const int oy = 2 * my + (p >> 1);
                const int ox = 2 * xx + (p & 1);
                out[(((size_t)(n * 3 + co)) << 16) + oy * 256 + ox]
                    = acc[m][rr] + bias[co];
            }
        }
    }
}

// ---------------------------------------------------------------------------
// vqm2 (R10, validated): VQ via MFMA GEMM; writes zq fp32 NCHW + bf16 CL copy.
// ---------------------------------------------------------------------------
__global__ __launch_bounds__(256) void vqm2_k(
    const float* __restrict__ ze, const u16* __restrict__ cb,
    const float* __restrict__ cn, const float* __restrict__ cbk,
    float* __restrict__ zq, u16* __restrict__ zqcl)
{
    __shared__ float CN[512];
    __shared__ int IDX[64];
    __shared__ u16 CLDS[64][66];
    const int tid = threadIdx.x;
    const int l = tid & 63, wvi = tid >> 6;
    const int ln = l & 15, kg = l >> 4;

    const int n = blockIdx.x >> 6, y = blockIdx.x & 63;

    for (int i = tid; i < 512; i += 256) CN[i] = cn[i];
    __syncthreads();

    short8 az[2];
#pragma unroll
    for (int ks = 0; ks < 2; ks++) {
        const float* zp = ze + ((size_t)(n * 64 + wvi * 16 + ln) * 64 + y) * 64
                          + ks * 32 + 8 * kg;
        short8 t;
#pragma unroll
        for (int j = 0; j < 8; j++) t[j] = (short)f2bf(zp[j]);
        az[ks] = t;
    }

    float bval[4] = {3.4e38f, 3.4e38f, 3.4e38f, 3.4e38f};
    int bidx[4] = {0, 0, 0, 0};
    for (int nt = 0; nt < 32; nt++) {
        const int code = nt * 16 + ln;
        const short8 b0 = *(const short8*)(cb + (size_t)code * 64 + 8 * kg);
        const short8 b1 = *(const short8*)(cb + (size_t)code * 64 + 32 + 8 * kg);
        f32x4 d = (f32x4){0.f, 0.f, 0.f, 0.f};
        d = __builtin_amdgcn_mfma_f32_16x16x32_bf16(az[0], b0, d, 0, 0, 0);
        d = __builtin_amdgcn_mfma_f32_16x16x32_bf16(az[1], b1, d, 0, 0, 0);
        const float cnv = CN[code];
#pragma unroll
        for (int r = 0; r < 4; r++) {
            const float dist = cnv - 2.f * d[r];
            if (dist < bval[r]) { bval[r] = dist; bidx[r] = code; }
        }
    }
#pragma unroll
    for (int off = 1; off < 16; off <<= 1) {
#pragma unroll
        for (int r = 0; r < 4; r++) {
            const float ov = __shfl_xor(bval[r], off);
            const int oi = __shfl_xor(bidx[r], off);
            if (ov < bval[r] || (ov == bval[r] && oi < bidx[r])) {
                bval[r] = ov; bidx[r] = oi;
            }
        }
    }
    if (ln == 0) {
#pragma unroll
        for (int r = 0; r < 4; r++) IDX[wvi * 16 + 4 * kg + r] = bidx[r];
    }
    __syncthreads();

    {
        const int ci = tid >> 2, ch4 = tid & 3;
        const int bi = IDX[ci];
        const float4* sp = (const float4*)(cbk + (size_t)bi * 64 + ch4 * 16);
        float4* dp = (float4*)(zq + ((size_t)(n * 64 + ci) * 64 + y) * 64 + ch4 * 16);
#pragma unroll
        for (int q = 0; q < 4; q++) dp[q] = sp[q];
    }

    for (int idx = tid; idx < 4096; idx += 256) {
        const int ci = idx >> 6, xx = idx & 63;
        CLDS[ci][xx] = cb[(size_t)IDX[ci] * 64 + xx];
    }
    __syncthreads();
    for (int idx = tid; idx < 4096; idx += 256) {
        const int xx = idx >> 6, ci = idx & 63;
        zqcl[(((size_t)(n * 64 + y) * 64 + xx) << 6) + ci] = CLDS[ci][xx];
    }
}

// ---------------------------------------------------------------------------
extern "C" void kernel_launch(void* const* d_in, const int* in_sizes, int n_in,
                              void* d_out, int out_size, void* d_ws, size_t ws_size,
                              hipStream_t stream)
{
    (void)in_sizes; (void)n_in; (void)out_size; (void)ws_size;

    const float* x   = (const float*)d_in[0];
    const float* ew1 = (const float*)d_in[1];
    const float* eb1 = (const float*)d_in[2];
    const float* ew2 = (const float*)d_in[3];
    const float* eb2 = (const float*)d_in[4];
    const float* ew3 = (const float*)d_in[5];
    const float* eb3 = (const float*)d_in[6];
    const float* cbk = (const float*)d_in[7];
    const float* dw1 = (const float*)d_in[8];
    const float* db1 = (const float*)d_in[9];
    const float* dw2 = (const float*)d_in[10];
    const float* db2 = (const float*)d_in[11];
    const float* dw3 = (const float*)d_in[12];
    const float* db3 = (const float*)d_in[13];

    u16* P    = (u16*)d_ws;
    u16* ZQCL = P;
    u16* A2   = P;
    u16* B = (u16*)((char*)d_ws + 134217728);
    u16* XCL = B;
    u16* Wg2 = (u16*)((char*)d_ws + 167772160);       // 262144
    u16* Wg3 = Wg2 + 262144;                          // 73728
    u16* Wg4 = Wg3 + 73728;                           // 73728
    u16* Wg5 = Wg4 + 73728;                           // 262144
    u16* Wg6 = Wg5 + 262144;                          // 18432 (dec3m)
    u16* CB  = Wg6 + 32768;                           // 32768
    u16* Wg1 = CB + 32768;                            // 8192
    float* CNg = (float*)(Wg1 + 8192);                // 512

    float* xr = (float*)d_out;
    float* ze = xr + (size_t)32 * 3 * 256 * 256;
    float* zq = ze + (size_t)32 * 64 * 64 * 64;

    g_enc1<<<32, 256, 0, stream>>>(ew1, Wg1);
    g_enc2<<<1024, 256, 0, stream>>>(ew2, Wg2);
    g_k3<<<288, 256, 0, stream>>>(ew3, Wg3, 128, 64);
    g_k3<<<288, 256, 0, stream>>>(dw1, Wg4, 64, 128);
    g_dec2<<<1024, 256, 0, stream>>>(dw2, Wg5);
    g_dec3m<<<72, 256, 0, stream>>>(dw3, Wg6);
    g_cbk<<<128, 256, 0, stream>>>(cbk, CB, CNg);

    xcl_k<<<32 * 258, 256, 0, stream>>>(x, XCL);
    enc1m_k<<<32 * 128, 256, 0, stream>>>(XCL, Wg1, eb1, P);
    // enc2: 4 planes k2 -> B (CL, relu)
    conv_mx3<2, 2, 4, 4, 128, 0><<<32 * 16, 512, 0, stream>>>(P, Wg2, eb2, B, 128);
    // enc3: k3 -> ze (fp32)
    conv_mx3<3, 3, 1, 2, 128, 1><<<32 * 8, 512, 0, stream>>>(B, Wg3, eb3, ze, 64);
    // VQ (writes zq fp32 + ZQCL bf16 CL)
    vqm2_k<<<2048, 256, 0, stream>>>(ze, CB, CNg, cbk, zq, ZQCL);
    // dec1: k3 -> B (CL, relu)
    conv_mx3<3, 3, 1, 4, 64, 0><<<32 * 16, 512, 0, stream>>>(ZQCL, Wg4, db1, B, 128);
    // deconv2: R12 dec2f -> A2 (CL, relu)
    dec2f_k<<<1024, 512, 0, stream>>>(B, Wg5, db2, A2);
    // deconv3 -> x_recon
    dec3m_k<<<1024, 256, 0, stream>>>(A2, Wg6, db3, xr);
}

// Round 19
// 547.704 us; speedup vs baseline: 1.0474x; 1.0291x over previous
//
#include <hip/hip_runtime.h>
#include <hip/hip_bf16.h>

// VQ-VAE forward. R19: R18 (locked best) + all 7 weight gathers and the
// x->channel-last transform fused into ONE flat-indexed kernel (g_all_k).
// Per-element formulas identical to the validated g_* / xcl_k kernels.

typedef unsigned short u16;
typedef unsigned int u32;
typedef unsigned long long u64;
typedef __attribute__((ext_vector_type(8))) short short8;
typedef __attribute__((ext_vector_type(4))) float f32x4;

__device__ __forceinline__ float bf2f(u16 u) {
    union { u32 i; float f; } x; x.i = ((u32)u) << 16; return x.f;
}
__device__ __forceinline__ u16 f2bf(float f) {
    __hip_bfloat16 h = __float2bfloat16(f);
    return *reinterpret_cast<u16*>(&h);
}

// ---------------------------------------------------------------------------
// Fused preprocessing: all weight gathers + codebook prep + x->CL transform.
// Flat task ranges (validated formulas copied verbatim):
//  T0 enc1    [0,       8192)
//  T1 enc2    [...,  +262144)
//  T2 k3 ew3  [...,   +73728)   CIN=128 COUT=64
//  T3 k3 dw1  [...,   +73728)   CIN=64  COUT=128
//  T4 dec2    [...,  +262144)
//  T5 dec3m   [...,   +18432)
//  T6 cbk     [...,   +32768)
//  T7 xcl     [..., +2130048)
// ---------------------------------------------------------------------------
__global__ __launch_bounds__(256) void g_all_k(
    const float* __restrict__ ew1, const float* __restrict__ ew2,
    const float* __restrict__ ew3, const float* __restrict__ dw1,
    const float* __restrict__ dw2, const float* __restrict__ dw3,
    const float* __restrict__ cbk, const float* __restrict__ x,
    u16* __restrict__ Wg1, u16* __restrict__ Wg2, u16* __restrict__ Wg3,
    u16* __restrict__ Wg4, u16* __restrict__ Wg5, u16* __restrict__ Wg6,
    u16* __restrict__ CB, float* __restrict__ CNg, u16* __restrict__ xcl)
{
    long idx = (long)blockIdx.x * 256 + threadIdx.x;

    // T0: enc1 weights  wg[co*64 + ky*16 + kx*4 + ci], ci 3->4 zero pad
    if (idx < 8192) {
        int ci = idx & 3, kx = (idx >> 2) & 3, ky = (idx >> 4) & 3, co = idx >> 6;
        float v = 0.f;
        if (ci < 3) v = ew1[((co * 3 + ci) * 4 + ky) * 4 + kx];
        Wg1[idx] = f2bf(v);
        return;
    }
    idx -= 8192;

    // T1: enc2 k4s2 -> 4 input-parity planes, 2x2 taps
    if (idx < 262144) {
        int ci = idx & 127, co = ((int)idx >> 7) & 127,
            s = ((int)idx >> 14) & 3, p = (int)idx >> 16;
        int a = p >> 1, b = p & 1, j = s >> 1, i = s & 1;
        int ky = (1 - a) + 2 * j, kx = (1 - b) + 2 * i;
        Wg2[idx] = f2bf(ew2[((co << 7 | ci) << 4) + ky * 4 + kx]);
        return;
    }
    idx -= 262144;

    // T2: k3 gather ew3 (CIN=128, COUT=64)
    if (idx < 73728) {
        int ci = idx % 128;
        int co = ((int)idx / 128) % 64;
        int s  = (int)idx / (128 * 64);
        Wg3[idx] = f2bf(ew3[(co * 128 + ci) * 9 + s]);
        return;
    }
    idx -= 73728;

    // T3: k3 gather dw1 (CIN=64, COUT=128)
    if (idx < 73728) {
        int ci = idx % 64;
        int co = ((int)idx / 64) % 128;
        int s  = (int)idx / (64 * 128);
        Wg4[idx] = f2bf(dw1[(co * 64 + ci) * 9 + s]);
        return;
    }
    idx -= 73728;

    // T4: dec2 k4s2p2 -> 4 output parities, 2x2 taps, IOHW flipped
    if (idx < 262144) {
        int ci = idx & 127, co = ((int)idx >> 7) & 127,
            s = ((int)idx >> 14) & 3, p = (int)idx >> 16;
        int py = p >> 1, px = p & 1, j = s >> 1, i = s & 1;
        Wg5[idx] = f2bf(dw2[((ci << 7 | co) << 4)
                            + (3 - (py + 2 * j)) * 4 + (3 - (px + 2 * i))]);
        return;
    }
    idx -= 262144;

    // T5: dec3 parity-packed
    if (idx < 18432) {
        int ci  = idx & 127;
        int row = ((int)idx >> 7) & 15;
        int t   = (int)idx >> 11;
        int dy = t / 3 - 1, dx = t % 3 - 1;
        float v = 0.f;
        if (row < 12) {
            int p = row / 3, co = row % 3;
            int py = p >> 1, px = p & 1;
            int a = dy + 1 - py, b2 = dx + 1 - px;
            if (a >= 0 && a <= 1 && b2 >= 0 && b2 <= 1)
                v = dw3[((ci * 3 + co) * 4 + (3 - (py + 2 * a))) * 4
                        + (3 - (px + 2 * b2))];
        }
        Wg6[idx] = f2bf(v);
        return;
    }
    idx -= 18432;

    // T6: codebook bf16 copy + norms
    if (idx < 32768) {
        CB[idx] = f2bf(cbk[idx]);
        if (idx < 512) {
            float s = 0.f;
            const float* r = cbk + idx * 64;
            for (int i = 0; i < 64; i++) s += r[i] * r[i];
            CNg[idx] = s;
        }
        return;
    }
    idx -= 32768;

    // T7: x (fp32 NCHW) -> x_cl[n][258][258][4] bf16 (one pixel per task)
    if (idx < 2130048) {
        const int xx = idx % 258;
        const int rem = (int)(idx / 258);
        const int y = rem % 258;
        const int n = rem / 258;
        const int gy = y - 1, gx = xx - 1;
        u16 pk[4] = {0, 0, 0, 0};
        if (gy >= 0 && gy < 256 && gx >= 0 && gx < 256) {
            const size_t base = ((size_t)n * 3 * 256 + gy) * 256 + gx;
            pk[0] = f2bf(x[base]);
            pk[1] = f2bf(x[base + 65536]);
            pk[2] = f2bf(x[base + 131072]);
        }
        *(u64*)(xcl + ((size_t)(n * 258 + y) * 258 + xx) * 4) = *(const u64*)pk;
    }
}

// ---------------------------------------------------------------------------
// enc1 via MFMA (R7, validated).
// ---------------------------------------------------------------------------
__global__ __launch_bounds__(256) void enc1m_k(
    const u16* __restrict__ xcl, const u16* __restrict__ wg,
    const float* __restrict__ bias, u16* __restrict__ P)
{
    const int tid = threadIdx.x;
    const int l = tid & 63, w = tid >> 6;
    const int ln = l & 15, kg = l >> 4;
    const int px = w >> 1, half = w & 1;

    const int oy = blockIdx.x & 127;
    const int n  = blockIdx.x >> 7;
    const int p  = (oy & 1) * 2 + px;
    const int yy = oy >> 1;

    short8 af[8][2];
#pragma unroll
    for (int u = 0; u < 8; u++)
#pragma unroll
        for (int s = 0; s < 2; s++)
            af[u][s] = *(const short8*)(wg + ((u * 16 + ln) << 6) + s * 32 + 8 * kg);

    const u16* xn = xcl + (size_t)n * 258 * 258 * 4;
    const int r0 = 2 * oy;

#pragma unroll
    for (int t = 0; t < 2; t++) {
        const int xq = half * 32 + t * 16 + ln;
        const int ox = px + 2 * xq;

        short8 bf[2];
#pragma unroll
        for (int s = 0; s < 2; s++) {
            const int row = r0 + 2 * s + (kg >> 1);
            bf[s] = *(const short8*)(xn + ((size_t)row * 258 + 2 * ox) * 4
                                     + (kg & 1) * 8);
        }

        f32x4 acc[8];
#pragma unroll
        for (int u = 0; u < 8; u++) acc[u] = (f32x4){0.f, 0.f, 0.f, 0.f};
#pragma unroll
        for (int u = 0; u < 8; u++) {
            acc[u] = __builtin_amdgcn_mfma_f32_16x16x32_bf16(af[u][0], bf[0], acc[u], 0, 0, 0);
            acc[u] = __builtin_amdgcn_mfma_f32_16x16x32_bf16(af[u][1], bf[1], acc[u], 0, 0, 0);
        }

#pragma unroll
        for (int u = 0; u < 8; u++) {
            const int cobase = u * 16 + 4 * kg;
            u16 pk[4];
#pragma unroll
            for (int r = 0; r < 4; r++)
                pk[r] = f2bf(fmaxf(acc[u][r] + bias[cobase + r], 0.f));
            *(u64*)(P + ((((size_t)(n * 4 + p) * 64 + yy) * 64 + xq) << 7) + cobase)
                = *(const u64*)pk;
        }
    }
}

// ---------------------------------------------------------------------------
// conv_mx3 (R9, validated): used for enc2/enc3/dec1.
// ---------------------------------------------------------------------------
template<int J, int I, int NP, int NCW, int CI, int OUTM>
__global__ __launch_bounds__(512) void conv_mx3(
    const u16* __restrict__ x, const u16* __restrict__ wg,
    const float* __restrict__ bias, void* __restrict__ yv,
    int COUT)
{
    constexpr int G = 8 / NCW;
    constexpr int RS = 2 * G + 2;
    constexpr int TASKS = RS * 68 * 4;
    constexpr int SLOTS = (TASKS + 511) / 512;
    constexpr int CHP = CI / 32;
    constexpr int NCHUNK = NP * CHP;
    __shared__ u16 XL[RS * 68 * 40];

    const int tid = threadIdx.x;
    const int l = tid & 63, wv = tid >> 6;
    const int kg = l >> 4, ln = l & 15;
    const int cw = wv % NCW, g = wv / NCW;

    int b = blockIdx.x;
    constexpr int TILES = 64 / (2 * G);
    const int tile = b % TILES;  b /= TILES;
    const int n = b;
    const int OY0 = tile * (2 * G);

    bool valid[SLOTS], okm[SLOTS];
    int goff[SLOTS], loff[SLOTS];
#pragma unroll
    for (int s = 0; s < SLOTS; s++) {
        const int idx = s * 512 + tid;
        valid[s] = idx < TASKS;
        const int q = idx & 3, cc = (idx >> 2) % 68, r = (idx >> 2) / 68;
        const int gr = OY0 - 1 + r, gx = cc - 1;
        okm[s] = valid[s] && gr >= 0 && gr < 64 && gx >= 0 && gx < 64;
        goff[s] = okm[s] ? ((gr * 64 + gx) * CI + 8 * q) : 0;
        loff[s] = (r * 68 + cc) * 40 + 8 * q;
    }

    f32x4 acc[2][8];
#pragma unroll
    for (int u = 0; u < 2; u++)
#pragma unroll
        for (int t = 0; t < 8; t++) acc[u][t] = (f32x4){0.f, 0.f, 0.f, 0.f};

    const u16* xn = x + (size_t)n * NP * CI * 4096;
    const int co0 = cw * 32 + ln;
    const short8 z8 = (short8){0, 0, 0, 0, 0, 0, 0, 0};

    short8 pf[SLOTS];
    {
        const u16* xp = xn;
#pragma unroll
        for (int s = 0; s < SLOTS; s++)
            pf[s] = okm[s] ? *(const short8*)(xp + goff[s]) : z8;
    }

    for (int c = 0; c < NCHUNK; c++) {
        __syncthreads();
#pragma unroll
        for (int s = 0; s < SLOTS; s++)
            if (valid[s]) *(short8*)(XL + loff[s]) = pf[s];
        __syncthreads();

        if (c + 1 < NCHUNK) {
            const int cn_ = c + 1;
            const u16* xp = xn + (size_t)(cn_ / CHP) * CI * 4096
                            + (cn_ % CHP) * 32;
#pragma unroll
            for (int s = 0; s < SLOTS; s++)
                pf[s] = okm[s] ? *(const short8*)(xp + goff[s]) : z8;
        }

        const int p = c / CHP;
        const int ci0 = (c % CHP) * 32;
        int dy0, dx0;
        const u16* wgp;
        if (NP == 4) {
            dy0 = -(p >> 1); dx0 = -(p & 1);
            wgp = wg + (size_t)p * J * I * COUT * CI;
        } else {
            dy0 = -1; dx0 = -1; wgp = wg;
        }

#define TAP_ROW(jv)                                                          \
        {                                                                    \
            short8 wf0[I], wf1[I];                                           \
            _Pragma("unroll")                                                \
            for (int i = 0; i < I; i++) {                                    \
                const size_t wb = ((size_t)((jv) * I + i) * COUT + co0)      \
                                  * CI + ci0 + 8 * kg;                       \
                wf0[i] = *(const short8*)(wgp + wb);                         \
                wf1[i] = *(const short8*)(wgp + wb + (size_t)16 * CI);       \
            }                                                                \
            _Pragma("unroll")                                                \
            for (int i = 0; i < I; i++) {                                    \
                _Pragma("unroll")                                            \
                for (int t = 0; t < 8; t++) {                                \
                    const int rf = (t >> 2) + 2 * g + dy0 + 1 + (jv);        \
                    const int cf = (t & 3) * 16 + ln + dx0 + 1 + i;          \
                    const short8 bf = *(const short8*)(                      \
                        XL + (rf * 68 + cf) * 40 + 8 * kg);                  \
                    acc[0][t] = __builtin_amdgcn_mfma_f32_16x16x32_bf16(     \
                        wf0[i], bf, acc[0][t], 0, 0, 0);                     \
                    acc[1][t] = __builtin_amdgcn_mfma_f32_16x16x32_bf16(     \
                        wf1[i], bf, acc[1][t], 0, 0, 0);                     \
                }                                                            \
            }                                                                \
        }

        if constexpr (J == 2) {
            TAP_ROW(0); TAP_ROW(1);
        } else {
            TAP_ROW(0); TAP_ROW(1); TAP_ROW(2);
        }
#undef TAP_ROW
    }

#pragma unroll
    for (int u = 0; u < 2; u++) {
        const int cob = cw * 32 + u * 16 + 4 * kg;
#pragma unroll
        for (int t = 0; t < 8; t++) {
            const int oy = OY0 + 2 * g + (t >> 2);
            const int ox = (t & 3) * 16 + ln;
            if constexpr (OUTM == 1) {
                float* out = (float*)yv;
#pragma unroll
                for (int rr = 0; rr < 4; rr++)
                    out[(((size_t)n * COUT + cob + rr) * 64 + oy) * 64 + ox]
                        = acc[u][t][rr] + bias[cob + rr];
            } else {
                u16 pk[4];
#pragma unroll
                for (int rr = 0; rr < 4; rr++)
                    pk[rr] = f2bf(fmaxf(acc[u][t][rr] + bias[cob + rr], 0.f));
                *(u64*)((u16*)yv + ((size_t)(n * 64 + oy) * 64 + ox) * COUT
                        + cob) = *(const u64*)pk;
            }
        }
    }
}

// ---------------------------------------------------------------------------
// dec2f (R12 exact, session-best): parity-per-wave, shared B-window,
// per-chunk staging, LDS-transpose epilogue (full-line stores).
// ---------------------------------------------------------------------------
__global__ __launch_bounds__(512) void dec2f_k(
    const u16* __restrict__ x, const u16* __restrict__ wg,
    const float* __restrict__ bias, u16* __restrict__ y)
{
    constexpr int RS = 4;
    constexpr int TASKS = RS * 68 * 4;       // 1088
    constexpr int SLOTS = 3;
    __shared__ u16 XL[RS * 68 * 40];
    __shared__ u16 LW[8 * 16 * 136];

    const int tid = threadIdx.x;
    const int l = tid & 63, wv = tid >> 6;
    const int kg = l >> 4, ln = l & 15;
    const int pc = wv & 3, ch = wv >> 2;
    const int py = pc >> 1, px = pc & 1;

    int b = blockIdx.x;
    const int tile = b & 31;  b >>= 5;
    const int n = b;
    const int OY0 = tile * 2;

    bool valid[SLOTS], okm[SLOTS];
    int goff[SLOTS], loff[SLOTS];
#pragma unroll
    for (int s = 0; s < SLOTS; s++) {
        const int idx = s * 512 + tid;
        valid[s] = idx < TASKS;
        const int q = idx & 3, cc = (idx >> 2) % 68, r = (idx >> 2) / 68;
        const int gr = OY0 - 1 + r, gx = cc - 1;
        okm[s] = valid[s] && gr >= 0 && gr < 64 && gx >= 0 && gx < 64;
        goff[s] = okm[s] ? ((gr * 64 + gx) * 128 + 8 * q) : 0;
        loff[s] = (r * 68 + cc) * 40 + 8 * q;
    }

    f32x4 acc[8][4];
#pragma unroll
    for (int u = 0; u < 8; u++)
#pragma unroll
        for (int t = 0; t < 4; t++) acc[u][t] = (f32x4){0.f, 0.f, 0.f, 0.f};

    const u16* xn = x + (size_t)n * 64 * 64 * 128;
    const short8 z8 = (short8){0, 0, 0, 0, 0, 0, 0, 0};
    const u16* wgp = wg + (size_t)pc * 4 * 128 * 128;

    short8 pf[SLOTS];
#pragma unroll
    for (int s = 0; s < SLOTS; s++)
        pf[s] = okm[s] ? *(const short8*)(xn + goff[s]) : z8;

    for (int c = 0; c < 4; c++) {
        __syncthreads();
#pragma unroll
        for (int s = 0; s < SLOTS; s++)
            if (valid[s]) *(short8*)(XL + loff[s]) = pf[s];
        __syncthreads();

        if (c < 3) {
            const u16* xp = xn + (c + 1) * 32;
#pragma unroll
            for (int s = 0; s < SLOTS; s++)
                pf[s] = okm[s] ? *(const short8*)(xp + goff[s]) : z8;
        }

        const int ci0 = c * 32;

        short8 B3[3][2][2];
#pragma unroll
        for (int rw = 0; rw < 3; rw++) {
            const int rf = py + rw;
#pragma unroll
            for (int cb = 0; cb < 2; cb++) {
                const int cf0 = ch * 32 + cb * 16 + ln + px;
#pragma unroll
                for (int sh = 0; sh < 2; sh++)
                    B3[rw][sh][cb] = *(const short8*)(
                        XL + (rf * 68 + cf0 + sh) * 40 + 8 * kg);
            }
        }

#pragma unroll
        for (int u = 0; u < 8; u++) {
            short8 wf[4];
#pragma unroll
            for (int s4 = 0; s4 < 4; s4++)
                wf[s4] = *(const short8*)(
                    wgp + ((size_t)s4 * 128 + u * 16 + ln) * 128 + ci0 + 8 * kg);
#pragma unroll
            for (int m = 0; m < 2; m++)
#pragma unroll
                for (int cb = 0; cb < 2; cb++)
#pragma unroll
                    for (int j = 0; j < 2; j++)
#pragma unroll
                        for (int i = 0; i < 2; i++)
                            acc[u][m * 2 + cb] =
                                __builtin_amdgcn_mfma_f32_16x16x32_bf16(
                                    wf[j * 2 + i], B3[m + j][i][cb],
                                    acc[u][m * 2 + cb], 0, 0, 0);
        }
    }

    // epilogue: LDS transpose per t-round, then contiguous 16B/lane stores.
    u16* lw = LW + wv * 16 * 136;
    const int q4 = l >> 4, ln15 = l & 15;
#pragma unroll
    for (int t = 0; t < 4; t++) {
        const int m = t >> 1, cb = t & 1;
#pragma unroll
        for (int u = 0; u < 8; u++) {
            const int cob = u * 16 + 4 * kg;
            u16 pk[4];
#pragma unroll
            for (int rr = 0; rr < 4; rr++)
                pk[rr] = f2bf(fmaxf(acc[u][t][rr] + bias[cob + rr], 0.f));
            *(u64*)(lw + ln * 136 + cob) = *(const u64*)pk;
        }
        asm volatile("s_waitcnt lgkmcnt(0)" ::: "memory");
        __builtin_amdgcn_sched_barrier(0);
        const int OY = 2 * (OY0 + m) + py;
#pragma unroll
        for (int rr2 = 0; rr2 < 4; rr2++) {
            const int pos = rr2 * 4 + q4;
            const short8 v = *(const short8*)(lw + pos * 136 + ln15 * 8);
            const int ox = ch * 32 + cb * 16 + pos;
            const int OX = 2 * ox + px;
            *(short8*)(y + ((size_t)(n * 128 + OY) * 128 + OX) * 128 + ln15 * 8) = v;
        }
        asm volatile("s_waitcnt lgkmcnt(0)" ::: "memory");
        __builtin_amdgcn_sched_barrier(0);
    }
}

// ---------------------------------------------------------------------------
// dec3m (R8, validated): deconv3 via parity-packed MFMA.
// ---------------------------------------------------------------------------
__global__ __launch_bounds__(256) void dec3m_k(
    const u16* __restrict__ A2, const u16* __restrict__ wg,
    const float* __restrict__ bias, float* __restrict__ out)
{
    const int tid = threadIdx.x;
    const int l = tid & 63, wvi = tid >> 6;
    const int ln = l & 15, kg = l >> 4;

    int b = blockIdx.x;
    const int mxT = b & 7;  b >>= 3;
    const int myT = b & 3;  b >>= 2;
    const int n = b;
    const int X0 = mxT * 16;
    const int MY0 = myT * 32 + wvi * 8;
    const int xx = X0 + ln;

    const short8 z8 = (short8){0, 0, 0, 0, 0, 0, 0, 0};

    f32x4 acc[8];
#pragma unroll
    for (int m = 0; m < 8; m++) acc[m] = (f32x4){0.f, 0.f, 0.f, 0.f};

    int xoff[3]; bool xok[3];
#pragma unroll
    for (int sh = 0; sh < 3; sh++) {
        const int xv = xx + sh - 1;
        xok[sh] = (xv >= 0) & (xv < 128);
        xoff[sh] = (xok[sh] ? xv : 0) << 7;
    }

    for (int ks = 0; ks < 4; ks++) {
        const int cio = ks * 32 + 8 * kg;

        short8 at[9];
#pragma unroll
        for (int t = 0; t < 9; t++)
            at[t] = *(const short8*)(wg + (((size_t)t * 16 + ln) << 7) + cio);

        short8 B[10][3];
#pragma unroll
        for (int r = 0; r < 10; r++) {
            const int yy = MY0 - 1 + r;
            const bool yok = (yy >= 0) & (yy < 128);
            const size_t rowb = ((size_t)(n * 128 + (yok ? yy : 0)) << 7 << 7);
#pragma unroll
            for (int sh = 0; sh < 3; sh++) {
                short8 v = *(const short8*)(A2 + rowb + xoff[sh] + cio);
                B[r][sh] = (yok & xok[sh]) ? v : z8;
            }
            if (r >= 2) {
                const int m = r - 2;
#pragma unroll
                for (int rr = 0; rr < 3; rr++)
#pragma unroll
                    for (int sh = 0; sh < 3; sh++)
                        acc[m] = __builtin_amdgcn_mfma_f32_16x16x32_bf16(
                            at[rr * 3 + sh], B[m + rr][sh], acc[m], 0, 0, 0);
            }
        }
    }

    if (kg < 3) {
#pragma unroll
        for (int m = 0; m < 8; m++) {
            const int my = MY0 + m;
#pragma unroll
            for (int rr = 0; rr < 4; rr++) {
                const int row = 4 * kg + rr;
                const int p = row / 3, co = row % 3;
                const int oy = 2 * my + (p >> 1);
                const int ox = 2 * xx + (p & 1);
                out[(((size_t)(n * 3 + co)) << 16) + oy * 256 + ox]
                    = acc[m][rr] + bias[co];
            }
        }
    }
}

// ---------------------------------------------------------------------------
// vqm2 (R10, validated): VQ via MFMA GEMM; writes zq fp32 NCHW + bf16 CL copy.
// ---------------------------------------------------------------------------
__global__ __launch_bounds__(256) void vqm2_k(
    const float* __restrict__ ze, const u16* __restrict__ cb,
    const float* __restrict__ cn, const float* __restrict__ cbk,
    float* __restrict__ zq, u16* __restrict__ zqcl)
{
    __shared__ float CN[512];
    __shared__ int IDX[64];
    __shared__ u16 CLDS[64][66];
    const int tid = threadIdx.x;
    const int l = tid & 63, wvi = tid >> 6;
    const int ln = l & 15, kg = l >> 4;

    const int n = blockIdx.x >> 6, y = blockIdx.x & 63;

    for (int i = tid; i < 512; i += 256) CN[i] = cn[i];
    __syncthreads();

    short8 az[2];
#pragma unroll
    for (int ks = 0; ks < 2; ks++) {
        const float* zp = ze + ((size_t)(n * 64 + wvi * 16 + ln) * 64 + y) * 64
                          + ks * 32 + 8 * kg;
        short8 t;
#pragma unroll
        for (int j = 0; j < 8; j++) t[j] = (short)f2bf(zp[j]);
        az[ks] = t;
    }

    float bval[4] = {3.4e38f, 3.4e38f, 3.4e38f, 3.4e38f};
    int bidx[4] = {0, 0, 0, 0};
    for (int nt = 0; nt < 32; nt++) {
        const int code = nt * 16 + ln;
        const short8 b0 = *(const short8*)(cb + (size_t)code * 64 + 8 * kg);
        const short8 b1 = *(const short8*)(cb + (size_t)code * 64 + 32 + 8 * kg);
        f32x4 d = (f32x4){0.f, 0.f, 0.f, 0.f};
        d = __builtin_amdgcn_mfma_f32_16x16x32_bf16(az[0], b0, d, 0, 0, 0);
        d = __builtin_amdgcn_mfma_f32_16x16x32_bf16(az[1], b1, d, 0, 0, 0);
        const float cnv = CN[code];
#pragma unroll
        for (int r = 0; r < 4; r++) {
            const float dist = cnv - 2.f * d[r];
            if (dist < bval[r]) { bval[r] = dist; bidx[r] = code; }
        }
    }
#pragma unroll
    for (int off = 1; off < 16; off <<= 1) {
#pragma unroll
        for (int r = 0; r < 4; r++) {
            const float ov = __shfl_xor(bval[r], off);
            const int oi = __shfl_xor(bidx[r], off);
            if (ov < bval[r] || (ov == bval[r] && oi < bidx[r])) {
                bval[r] = ov; bidx[r] = oi;
            }
        }
    }
    if (ln == 0) {
#pragma unroll
        for (int r = 0; r < 4; r++) IDX[wvi * 16 + 4 * kg + r] = bidx[r];
    }
    __syncthreads();

    {
        const int ci = tid >> 2, ch4 = tid & 3;
        const int bi = IDX[ci];
        const float4* sp = (const float4*)(cbk + (size_t)bi * 64 + ch4 * 16);
        float4* dp = (float4*)(zq + ((size_t)(n * 64 + ci) * 64 + y) * 64 + ch4 * 16);
#pragma unroll
        for (int q = 0; q < 4; q++) dp[q] = sp[q];
    }

    for (int idx = tid; idx < 4096; idx += 256) {
        const int ci = idx >> 6, xx = idx & 63;
        CLDS[ci][xx] = cb[(size_t)IDX[ci] * 64 + xx];
    }
    __syncthreads();
    for (int idx = tid; idx < 4096; idx += 256) {
        const int xx = idx >> 6, ci = idx & 63;
        zqcl[(((size_t)(n * 64 + y) * 64 + xx) << 6) + ci] = CLDS[ci][xx];
    }
}

// ---------------------------------------------------------------------------
extern "C" void kernel_launch(void* const* d_in, const int* in_sizes, int n_in,
                              void* d_out, int out_size, void* d_ws, size_t ws_size,
                              hipStream_t stream)
{
    (void)in_sizes; (void)n_in; (void)out_size; (void)ws_size;

    const float* x   = (const float*)d_in[0];
    const float* ew1 = (const float*)d_in[1];
    const float* eb1 = (const float*)d_in[2];
    const float* ew2 = (const float*)d_in[3];
    const float* eb2 = (const float*)d_in[4];
    const float* ew3 = (const float*)d_in[5];
    const float* eb3 = (const float*)d_in[6];
    const float* cbk = (const float*)d_in[7];
    const float* dw1 = (const float*)d_in[8];
    const float* db1 = (const float*)d_in[9];
    const float* dw2 = (const float*)d_in[10];
    const float* db2 = (const float*)d_in[11];
    const float* dw3 = (const float*)d_in[12];
    const float* db3 = (const float*)d_in[13];

    u16* P    = (u16*)d_ws;
    u16* ZQCL = P;
    u16* A2   = P;
    u16* B = (u16*)((char*)d_ws + 134217728);
    u16* XCL = B;
    u16* Wg2 = (u16*)((char*)d_ws + 167772160);       // 262144
    u16* Wg3 = Wg2 + 262144;                          // 73728
    u16* Wg4 = Wg3 + 73728;                           // 73728
    u16* Wg5 = Wg4 + 73728;                           // 262144
    u16* Wg6 = Wg5 + 262144;                          // 18432 (dec3m)
    u16* CB  = Wg6 + 32768;                           // 32768
    u16* Wg1 = CB + 32768;                            // 8192
    float* CNg = (float*)(Wg1 + 8192);                // 512

    float* xr = (float*)d_out;
    float* ze = xr + (size_t)32 * 3 * 256 * 256;
    float* zq = ze + (size_t)32 * 64 * 64 * 64;

    // fused preprocessing: all gathers + codebook prep + x->CL (one dispatch)
    g_all_k<<<11177, 256, 0, stream>>>(ew1, ew2, ew3, dw1, dw2, dw3, cbk, x,
                                       Wg1, Wg2, Wg3, Wg4, Wg5, Wg6,
                                       CB, CNg, XCL);

    enc1m_k<<<32 * 128, 256, 0, stream>>>(XCL, Wg1, eb1, P);
    // enc2: 4 planes k2 -> B (CL, relu)
    conv_mx3<2, 2, 4, 4, 128, 0><<<32 * 16, 512, 0, stream>>>(P, Wg2, eb2, B, 128);
    // enc3: k3 -> ze (fp32)
    conv_mx3<3, 3, 1, 2, 128, 1><<<32 * 8, 512, 0, stream>>>(B, Wg3, eb3, ze, 64);
    // VQ (writes zq fp32 + ZQCL bf16 CL)
    vqm2_k<<<2048, 256, 0, stream>>>(ze, CB, CNg, cbk, zq, ZQCL);
    // dec1: k3 -> B (CL, relu)
    conv_mx3<3, 3, 1, 4, 64, 0><<<32 * 16, 512, 0, stream>>>(ZQCL, Wg4, db1, B, 128);
    // deconv2: R12 dec2f -> A2 (CL, relu)
    dec2f_k<<<1024, 512, 0, stream>>>(B, Wg5, db2, A2);
    // deconv3 -> x_recon
    dec3m_k<<<1024, 256, 0, stream>>>(A2, Wg6, db3, xr);
}